// Round 15
// baseline (505.475 us; speedup 1.0000x reference)
//
#include <hip/hip_runtime.h>

// Round 15: occupancy attack — 1024 thr (16 waves = 4/SIMD), 1 block/CU,
// B-weights staged ONCE in LDS (128 KB, swizzled; enc overwritten by dec at
// the transition). 16 waves = 2 row-groups x 8 col-groups; each wave owns
// 32 rows x 64 gate-local cols -> acc[2][4] (32 regs) + crr (8) only;
// NO persistent weight regs -> fits 128-reg budget at 4 waves/SIMD.
// Obs fold stays in the K=32 MFMA x-block (A2/xw in LDS, 0 persistent regs).
// Decoder bias via acc-init movs from 4 scalar regs. 2 barriers/step
// (hL single-buffered: MM reads | barrier | GATE writes | barrier).
// All math identical to r14: prescaled weights (-log2e/-2log2e), exact
// hi/lo obs split, decoder pos-path folded into Whh_d, c in f32 regs,
// 4-bit XOR LDS swizzle everywhere (slot = (k>>3)^(row&15)).

#define OBS_LEN 8
#define PRED_LEN 12
#define BATCH 131072
#define HID 128
#define NZ 512
#define KWT 128

typedef float f32x4 __attribute__((ext_vector_type(4)));
typedef float f32x2 __attribute__((ext_vector_type(2)));
typedef unsigned short u16x8 __attribute__((ext_vector_type(8)));
typedef __bf16 bf16x8 __attribute__((ext_vector_type(8)));

#define K2F 1.4426950408889634f   // log2(e)

static __device__ __forceinline__ unsigned short cvt1(float f) {
  __bf16 b = (__bf16)f;
  return __builtin_bit_cast(unsigned short, b);
}
static __device__ __forceinline__ float bf2f(unsigned short h) {
  return __uint_as_float(((unsigned int)h) << 16);
}

// ---------------- prep ----------------
// Permuted col c: cg=c>>6, gate=(c>>4)&3, cl=c&15; unit=cg*16+cl; n=gate*128+unit.
// Scale s = -2*log2e for gate g (index 2), else -log2e.
// wt[c][k] = bf16(s * (Whh[k][n] (+ dec pos-fold)))   [linear; main kernel swizzles]
// enc: xw[c][0..7] = bf16(s*{wx,wy,bias,wx,wy,0,0,0}); dec: auxf[c] = f32 s*bias.
__global__ void prep_weights(const float* __restrict__ We,   const float* __restrict__ be,
                             const float* __restrict__ Wih_e,const float* __restrict__ Whh_e,
                             const float* __restrict__ b_e,
                             const float* __restrict__ Wd,   const float* __restrict__ bd,
                             const float* __restrict__ Wih_d,const float* __restrict__ Whh_d,
                             const float* __restrict__ b_d,
                             const float* __restrict__ Wo,   const float* __restrict__ bo,
                             unsigned short* __restrict__ wt_enc,
                             unsigned short* __restrict__ wt_dec,
                             unsigned short* __restrict__ xw_enc,
                             float* __restrict__ auxf_dec) {
  const int c = blockIdx.x & (NZ - 1);
  const bool dec = blockIdx.x >= NZ;
  const int cg = c >> 6, gate = (c >> 4) & 3, cl = c & 15;
  const int unit = cg * 16 + cl;
  const int n = gate * HID + unit;
  const float s = (gate == 2) ? (-2.f * K2F) : (-K2F);

  const float* Whh = dec ? Whh_d : Whh_e;
  const float* Wih = dec ? Wih_d : Wih_e;
  const float* Wem = dec ? Wd : We;
  const float* bem = dec ? bd : be;
  const float* bl  = dec ? b_d : b_e;
  unsigned short* wt = dec ? wt_dec : wt_enc;

  float wx = 0.f, wy = 0.f;
  for (int e = 0; e < HID; ++e) {
    wx += Wem[e] * Wih[e * NZ + n];
    wy += Wem[HID + e] * Wih[e * NZ + n];
  }
  for (int k = threadIdx.x; k < KWT; k += 64) {
    float v = Whh[k * NZ + n];
    if (dec) v += Wo[k * 2] * wx + Wo[k * 2 + 1] * wy;
    wt[c * KWT + k] = cvt1(s * v);
  }
  if (threadIdx.x == 0) {
    float bb = bl[n];
    for (int e = 0; e < HID; ++e) bb += bem[e] * Wih[e * NZ + n];
    if (dec) {
      bb += bo[0] * wx + bo[1] * wy;
      auxf_dec[c] = s * bb;
    } else {
      unsigned short* xr = xw_enc + c * 8;
      xr[0] = cvt1(s * wx); xr[1] = cvt1(s * wy); xr[2] = cvt1(s * bb);
      xr[3] = xr[0]; xr[4] = xr[1];
      xr[5] = 0; xr[6] = 0; xr[7] = 0;
    }
  }
}

// ---------------- main fused kernel ----------------
// MFMA 16x16x32 bf16 (HW-verified r1-r14):
//  A/B frag: row/col = lane&15, k = 32kc + (lane>>4)*8 + j
//  C/D: col = lane&15, row = (lane>>4)*4 + reg
// LDS swizzle (4-bit): elem(r,k) = r*128 + (((k>>3)^(r&15))<<3) + (k&7)

#define MFMA(A, B, C)                                                          \
  __builtin_amdgcn_mfma_f32_16x16x32_bf16(                                     \
      __builtin_bit_cast(bf16x8, (A)), __builtin_bit_cast(bf16x8, (B)), (C),   \
      0, 0, 0)

#define EXP4(D, S)                                                             \
  { f32x4 _s = (S);                                                            \
    D[0] = __builtin_amdgcn_exp2f(_s[0]); D[1] = __builtin_amdgcn_exp2f(_s[1]);\
    D[2] = __builtin_amdgcn_exp2f(_s[2]); D[3] = __builtin_amdgcn_exp2f(_s[3]); }
#define RCP4(D, S)                                                             \
  { f32x4 _r = (S);                                                            \
    D[0] = __builtin_amdgcn_rcpf(_r[0]); D[1] = __builtin_amdgcn_rcpf(_r[1]);  \
    D[2] = __builtin_amdgcn_rcpf(_r[2]); D[3] = __builtin_amdgcn_rcpf(_r[3]); }

// stage 512x128 weights global(linear) -> Wl (swizzled). 1024 thr, 128B each.
#define STAGE_WT(SRC)                                                          \
  { const int sw_c = tid >> 1, sw_h = (tid & 1) * 8;                           \
    const unsigned short* sw_s = (SRC) + sw_c * KWT + sw_h * 8;                \
    unsigned short* sw_d = Wl + sw_c * KWT;                                    \
    _Pragma("unroll")                                                          \
    for (int j = 0; j < 8; ++j)                                                \
      *(u16x8*)&sw_d[((sw_h + j) ^ (sw_c & 15)) << 3] =                        \
          *(const u16x8*)(sw_s + j * 8);                                       \
  }

// K=128 hidden matmul for own 32x64 tile (acc pre-initialized)
#define MMH()                                                                  \
  { _Pragma("unroll")                                                          \
    for (int kc = 0; kc < 4; ++kc) {                                           \
      const int sl = (((kc * 4 + l4) ^ l15) << 3);                            \
      u16x8 a0 = *(const u16x8*)&hL[(rbase + l15) * 128 + sl];                 \
      u16x8 a1 = *(const u16x8*)&hL[(rbase + 16 + l15) * 128 + sl];            \
      _Pragma("unroll")                                                        \
      for (int g = 0; g < 4; ++g) {                                            \
        u16x8 bf = *(const u16x8*)&Wl[(cg * 64 + g * 16 + l15) * 128 + sl];    \
        acc[0][g] = MFMA(a0, bf, acc[0][g]);                                   \
        acc[1][g] = MFMA(a1, bf, acc[1][g]);                                   \
      } } }

// encoder MM: K=32 x-block (A2/xw rows only valid at l4==0; others zero)
#define MMXE(Q)                                                                \
  { u16x8 za = (u16x8){0, 0, 0, 0, 0, 0, 0, 0};                                \
    u16x8 a2a = za, a2b = za, xf0 = za, xf1 = za, xf2 = za, xf3 = za;          \
    if (l4 == 0) {                                                             \
      a2a = *(const u16x8*)&A2[(Q)*512 + (rbase + l15) * 8];                   \
      a2b = *(const u16x8*)&A2[(Q)*512 + (rbase + 16 + l15) * 8];              \
      xf0 = *(const u16x8*)&xwL[(cg * 64 + l15) * 8];                          \
      xf1 = *(const u16x8*)&xwL[(cg * 64 + 16 + l15) * 8];                     \
      xf2 = *(const u16x8*)&xwL[(cg * 64 + 32 + l15) * 8];                     \
      xf3 = *(const u16x8*)&xwL[(cg * 64 + 48 + l15) * 8];                     \
    }                                                                          \
    acc[0][0] = MFMA(a2a, xf0, ZROV); acc[1][0] = MFMA(a2b, xf0, ZROV);        \
    acc[0][1] = MFMA(a2a, xf1, ZROV); acc[1][1] = MFMA(a2b, xf1, ZROV);        \
    acc[0][2] = MFMA(a2a, xf2, ZROV); acc[1][2] = MFMA(a2b, xf2, ZROV);        \
    acc[0][3] = MFMA(a2a, xf3, ZROV); acc[1][3] = MFMA(a2b, xf3, ZROV);        \
    MMH() }

// decoder acc init from scalar bias regs
#define INITD()                                                                \
  { _Pragma("unroll")                                                          \
    for (int m = 0; m < 2; ++m) {                                              \
      _Pragma("unroll")                                                        \
      for (int g = 0; g < 4; ++g)                                              \
        acc[m][g] = (f32x4){bbD[g], bbD[g], bbD[g], bbD[g]};                   \
    } }

// gate for own tile: acc = scaled z; writes h rows rbase+16m+l4*4+r
#define GATEC()                                                                \
  { _Pragma("unroll")                                                          \
    for (int m = 0; m < 2; ++m) {                                              \
      f32x4 g_eB, g_eA, g_eG, g_eO;                                            \
      EXP4(g_eB, acc[m][0]) EXP4(g_eA, acc[m][1])                              \
      EXP4(g_eG, acc[m][2]) EXP4(g_eO, acc[m][3])                              \
      f32x4 g_a1 = 1.f + g_eA, g_b1 = 1.f + g_eB, g_g1 = 1.f + g_eG;           \
      f32x4 g_bg = g_b1 * g_g1;                                                \
      f32x4 g_rd; RCP4(g_rd, g_a1 * g_bg)                                      \
      f32x4 g_cv = (crr[m] * g_bg + (1.f - g_eG) * g_a1) * g_rd;               \
      crr[m] = g_cv;                                                           \
      f32x4 g_eC; EXP4(g_eC, g_cv * (-2.f * K2F))                              \
      f32x4 g_rh; RCP4(g_rh, (1.f + g_eO) * (1.f + g_eC))                      \
      f32x4 g_hv = (1.f - g_eC) * g_rh;                                        \
      const int g_R0 = rbase + 16 * m + l4 * 4;                                \
      _Pragma("unroll")                                                        \
      for (int r = 0; r < 4; ++r)                                              \
        hL[(g_R0 + r) * 128 + ((uh ^ ((g_R0 + r) & 15)) << 3) + ul] =          \
            cvt1(g_hv[r]);                                                     \
    } }

// pos = h @ Wo + bo, fire-and-forget. 16 thr/row over all 64 rows.
#define POSC(S)                                                                \
  { const int pp_r = tid >> 4;                                                 \
    u16x8 pp_h =                                                               \
        *(const u16x8*)&hL[pp_r * 128 + ((pq ^ (pp_r & 15)) << 3)];            \
    const float* pp_w = Wo + pq * 16;                                          \
    f32x4 pw0 = *(const f32x4*)pp_w;                                           \
    f32x4 pw1 = *(const f32x4*)(pp_w + 4);                                     \
    f32x4 pw2 = *(const f32x4*)(pp_w + 8);                                     \
    f32x4 pw3 = *(const f32x4*)(pp_w + 12);                                    \
    f32x2 pp_s = (f32x2){0.f, 0.f};                                            \
    pp_s += bf2f(pp_h[0]) * (f32x2){pw0[0], pw0[1]};                           \
    pp_s += bf2f(pp_h[1]) * (f32x2){pw0[2], pw0[3]};                           \
    pp_s += bf2f(pp_h[2]) * (f32x2){pw1[0], pw1[1]};                           \
    pp_s += bf2f(pp_h[3]) * (f32x2){pw1[2], pw1[3]};                           \
    pp_s += bf2f(pp_h[4]) * (f32x2){pw2[0], pw2[1]};                           \
    pp_s += bf2f(pp_h[5]) * (f32x2){pw2[2], pw2[3]};                           \
    pp_s += bf2f(pp_h[6]) * (f32x2){pw3[0], pw3[1]};                           \
    pp_s += bf2f(pp_h[7]) * (f32x2){pw3[2], pw3[3]};                           \
    pp_s[0] += __shfl_xor(pp_s[0], 1); pp_s[1] += __shfl_xor(pp_s[1], 1);      \
    pp_s[0] += __shfl_xor(pp_s[0], 2); pp_s[1] += __shfl_xor(pp_s[1], 2);      \
    pp_s[0] += __shfl_xor(pp_s[0], 4); pp_s[1] += __shfl_xor(pp_s[1], 4);      \
    pp_s[0] += __shfl_xor(pp_s[0], 8); pp_s[1] += __shfl_xor(pp_s[1], 8);      \
    if (pq == 0) {                                                             \
      float2 pp_o; pp_o.x = pp_s[0] + bo0; pp_o.y = pp_s[1] + bo1;             \
      ((float2*)out)[(size_t)(S)*BATCH + row0 + pp_r] = pp_o;                  \
    } }

// stage A2 (64 rows x 8 u16) for step T into pbuf Q (exact hi/lo split)
#define STAGE_A2(T, Q)                                                         \
  if (tid < 64) {                                                              \
    float2 so_p = ((const float2*)obs)[(size_t)(T)*BATCH + row0 + tid];        \
    unsigned short so_x = cvt1(so_p.x), so_y = cvt1(so_p.y);                   \
    unsigned short* so_r = &A2[(Q)*512 + tid * 8];                             \
    so_r[0] = so_x; so_r[1] = so_y; so_r[2] = 0x3F80u;                         \
    so_r[3] = cvt1(so_p.x - bf2f(so_x));                                       \
    so_r[4] = cvt1(so_p.y - bf2f(so_y));                                       \
    so_r[5] = 0; so_r[6] = 0; so_r[7] = 0;                                     \
  }

// LDS (u16 units): Wl 65536 | hL 8192 | xwL 4096 | A2 1024  -> 157696 B
#define SMEM_BYTES ((NZ * KWT + 64 * 128 + NZ * 8 + 2 * 64 * 8) * 2)

__global__ __launch_bounds__(1024, 4) void lstm_fused(
    const float* __restrict__ obs,
    const unsigned short* __restrict__ wt_enc,
    const unsigned short* __restrict__ wt_dec,
    const unsigned short* __restrict__ xw_enc,
    const float* __restrict__ auxf_dec,
    const float* __restrict__ Wo, const float* __restrict__ bo,
    float* __restrict__ out) {
  extern __shared__ unsigned short sm[];
  unsigned short* Wl  = sm;                       // [512][128] swizzled
  unsigned short* hL  = sm + NZ * KWT;            // [64][128] swizzled
  unsigned short* xwL = hL + 64 * 128;            // [512][8]
  unsigned short* A2  = xwL + NZ * 8;             // [2][64][8]

  const int tid = threadIdx.x;
  const int lane = tid & 63;
  const int wv = tid >> 6;            // 0..15
  const int rg = wv >> 3, cg = wv & 7;
  const int rbase = rg * 32;          // own rows [rbase, rbase+32)
  const int l15 = lane & 15;
  const int l4 = lane >> 4;
  const int pq = tid & 15;
  const int row0 = blockIdx.x * 64;
  const int u = cg * 16 + l15, uh = u >> 3, ul = u & 7;
  const float bo0 = bo[0], bo1 = bo[1];
  const f32x4 ZROV = {0.f, 0.f, 0.f, 0.f};

  // ---- P0: stage enc weights (swizzled) + xw; zero hL + A2; A2(0) ----
  STAGE_WT(wt_enc)
  if (tid < NZ) *(u16x8*)&xwL[tid * 8] = *(const u16x8*)&xw_enc[tid * 8];
  {
    u16x8 z8 = (u16x8){0, 0, 0, 0, 0, 0, 0, 0};
    *(u16x8*)&hL[tid * 8] = z8;                   // 1024*8 = 8192 u16
    if (tid < 128) *(u16x8*)&A2[tid * 8] = z8;    // 1024 u16
  }
  STAGE_A2(0, 0)

  f32x4 acc[2][4];
  f32x4 crr[2];
  crr[0] = crr[1] = ZROV;
  __syncthreads();

  // ---- encoder t = 0..7: {MMXE | bar | GATE + stage A2(t+1) | bar} ----
#pragma unroll 1
  for (int t = 0; t < OBS_LEN; ++t) {
    const int q = t & 1;
    MMXE(q)                     // reads hL (h(t)), Wl, A2[q], xwL
    __syncthreads();            // all hL/Wl reads done
    GATEC()                     // writes h(t+1) into hL
    if (t + 1 < OBS_LEN) { STAGE_A2(t + 1, q ^ 1) }
    __syncthreads();
  }
  // hL = h_enc

  // ---- transition: overwrite Wl with decoder weights; bias regs ----
  STAGE_WT(wt_dec)              // enc Wl reads all completed at t=7 barrier
  float bbD[4];
#pragma unroll
  for (int g = 0; g < 4; ++g) bbD[g] = auxf_dec[cg * 64 + g * 16 + l15];
  crr[0] = crr[1] = ZROV;
  __syncthreads();

  // ---- decoder d = 1..11: {INITD+MMH, POSC(d-1) | bar | GATE | bar} ----
#pragma unroll 1
  for (int d = 1; d < PRED_LEN; ++d) {
    INITD()
    MMH()                       // reads hL = h(d-1), Wl
    POSC(d - 1)                 // reads hL = h(d-1) (pre-barrier, safe)
    __syncthreads();
    GATEC()                     // writes h(d)
    __syncthreads();
  }
  POSC(PRED_LEN - 1)
}

extern "C" void kernel_launch(void* const* d_in, const int* in_sizes, int n_in,
                              void* d_out, int out_size, void* d_ws, size_t ws_size,
                              hipStream_t stream) {
  const float* obs   = (const float*)d_in[0];
  const float* We    = (const float*)d_in[1];
  const float* be    = (const float*)d_in[2];
  const float* Wih_e = (const float*)d_in[3];
  const float* Whh_e = (const float*)d_in[4];
  const float* b_e   = (const float*)d_in[5];
  const float* Wd    = (const float*)d_in[6];
  const float* bd    = (const float*)d_in[7];
  const float* Wih_d = (const float*)d_in[8];
  const float* Whh_d = (const float*)d_in[9];
  const float* b_d   = (const float*)d_in[10];
  const float* Wo    = (const float*)d_in[11];
  const float* bo    = (const float*)d_in[12];
  float* out = (float*)d_out;

  unsigned short* wt_enc = (unsigned short*)d_ws;                 // 128 KB
  unsigned short* wt_dec = wt_enc + NZ * KWT;                     // +128 KB
  unsigned short* xw_enc = wt_dec + NZ * KWT;                     // +8 KB
  float* auxf_dec = (float*)(xw_enc + NZ * 8);                    // +2 KB

  hipFuncSetAttribute((const void*)lstm_fused,
                      hipFuncAttributeMaxDynamicSharedMemorySize, SMEM_BYTES);

  hipLaunchKernelGGL(prep_weights, dim3(2 * NZ), dim3(64), 0, stream,
                     We, be, Wih_e, Whh_e, b_e, Wd, bd, Wih_d, Whh_d, b_d,
                     Wo, bo, wt_enc, wt_dec, xw_enc, auxf_dec);
  hipLaunchKernelGGL(lstm_fused, dim3(BATCH / 64), dim3(1024), SMEM_BYTES,
                     stream, obs, wt_enc, wt_dec, xw_enc, auxf_dec, Wo, bo,
                     out);
}

// Round 16
// 489.956 us; speedup vs baseline: 1.0317x; 1.0317x over previous
//
#include <hip/hip_runtime.h>

// Round 16 = r13 base + intra-wave MM/GATE interleave + pk-f32 gate math.
// r15 proved occupancy is not the limiter (2x waves, same 500us): the MM
// (matrix pipe) and GATE (VALU/trans) sections serialize because each wave
// emits them as contiguous runs and all waves are phase-locked. Fix: within
// each phase the independent work (GATE of chunk Y || MM of chunk X) is
// interleaved at source granularity: G(m0) MM(kc0) G(m1) MM(kc1) POS
// MM(kc2) MM(kc3) -> a wave stalled on the gate's trans chain issues MFMAs.
// GATE rewritten on f32x2 (v_pk_* halves non-trans VALU); decoder bias rides
// the kc0 MFMA C-operand (bbV). Everything else r13: 512 thr (8 waves,
// 2/SIMD, spill-free), two 32-row chunks, 1 barrier/phase, 4-bit XOR LDS
// swizzle, prescaled weights (-log2e/-2log2e), encoder obs+bias as K=32
// MFMA fold (exact hi/lo), decoder pos-path folded into Whh_d, Wo in regs,
// c in f32 regs.

#define OBS_LEN 8
#define PRED_LEN 12
#define BATCH 131072
#define HID 128
#define NZ 512
#define KWT 128
#define XK 32
#define A2S 40          // A2 row stride (u16): 80B

typedef float f32x4 __attribute__((ext_vector_type(4)));
typedef float f32x2 __attribute__((ext_vector_type(2)));
typedef unsigned short u16x8 __attribute__((ext_vector_type(8)));
typedef __bf16 bf16x8 __attribute__((ext_vector_type(8)));

#define K2F 1.4426950408889634f   // log2(e)

static __device__ __forceinline__ unsigned short cvt1(float f) {
  __bf16 b = (__bf16)f;
  return __builtin_bit_cast(unsigned short, b);
}
static __device__ __forceinline__ float bf2f(unsigned short h) {
  return __uint_as_float(((unsigned int)h) << 16);
}

// ---------------- prep (r13-verified, unchanged) ----------------
__global__ void prep_weights(const float* __restrict__ We,   const float* __restrict__ be,
                             const float* __restrict__ Wih_e,const float* __restrict__ Whh_e,
                             const float* __restrict__ b_e,
                             const float* __restrict__ Wd,   const float* __restrict__ bd,
                             const float* __restrict__ Wih_d,const float* __restrict__ Whh_d,
                             const float* __restrict__ b_d,
                             const float* __restrict__ Wo,   const float* __restrict__ bo,
                             unsigned short* __restrict__ wt_enc,
                             unsigned short* __restrict__ wt_dec,
                             unsigned short* __restrict__ xw_enc,
                             float* __restrict__ auxf_dec) {
  const int c = blockIdx.x & (NZ - 1);
  const bool dec = blockIdx.x >= NZ;
  const int cg = c >> 6, gate = (c >> 4) & 3, cl = c & 15;
  const int unit = cg * 16 + cl;
  const int n = gate * HID + unit;
  const float s = (gate == 2) ? (-2.f * K2F) : (-K2F);

  const float* Whh = dec ? Whh_d : Whh_e;
  const float* Wih = dec ? Wih_d : Wih_e;
  const float* Wem = dec ? Wd : We;
  const float* bem = dec ? bd : be;
  const float* bl  = dec ? b_d : b_e;
  unsigned short* wt = dec ? wt_dec : wt_enc;

  float wx = 0.f, wy = 0.f;
  for (int e = 0; e < HID; ++e) {
    wx += Wem[e] * Wih[e * NZ + n];
    wy += Wem[HID + e] * Wih[e * NZ + n];
  }
  for (int k = threadIdx.x; k < KWT; k += 64) {
    float v = Whh[k * NZ + n];
    if (dec) v += Wo[k * 2] * wx + Wo[k * 2 + 1] * wy;
    wt[c * KWT + k] = cvt1(s * v);
  }
  if (threadIdx.x == 0) {
    float bb = bl[n];
    for (int e = 0; e < HID; ++e) bb += bem[e] * Wih[e * NZ + n];
    if (dec) {
      bb += bo[0] * wx + bo[1] * wy;
      auxf_dec[c] = s * bb;
    } else {
      unsigned short* xr = xw_enc + c * XK;
      for (int k = 5; k < XK; ++k) xr[k] = 0;
      xr[0] = cvt1(s * wx); xr[1] = cvt1(s * wy); xr[2] = cvt1(s * bb);
      xr[3] = xr[0]; xr[4] = xr[1];
    }
  }
}

// ---------------- main fused kernel ----------------
// MFMA 16x16x32 bf16 (HW-verified r1-r15):
//  A/B frag: row/col = lane&15, k = 32kc + (lane>>4)*8 + j
//  C/D: col = lane&15, row = (lane>>4)*4 + reg
// hL swizzle (4-bit): elem(r,k) = r*128 + (((k>>3)^(r&15))<<3) + (k&7)

#define MFMA(A, B, C)                                                          \
  __builtin_amdgcn_mfma_f32_16x16x32_bf16(                                     \
      __builtin_bit_cast(bf16x8, (A)), __builtin_bit_cast(bf16x8, (B)), (C),   \
      0, 0, 0)

#define LOADW_BF(WT)                                                           \
  { _Pragma("unroll")                                                          \
    for (int kc = 0; kc < 4; ++kc) {                                           \
      _Pragma("unroll")                                                        \
      for (int g = 0; g < 4; ++g)                                              \
        bfr[kc][g] =                                                           \
            *(const u16x8*)&(WT)[(cg * 64 + g * 16 + l15) * KWT + kc * 32 +    \
                                 l4 * 8];                                      \
    } }

// one kc-slice of the K=128 hidden matmul (accumulating)
#define MMH_KC(ACC, X, KC)                                                     \
  { const int mm_sl = ((((KC)*4 + l4) ^ l15) << 3);                            \
    u16x8 mm_a0 = *(const u16x8*)&hL[(X)*4096 + l15 * 128 + mm_sl];            \
    u16x8 mm_a1 = *(const u16x8*)&hL[(X)*4096 + (16 + l15) * 128 + mm_sl];     \
    _Pragma("unroll")                                                          \
    for (int g = 0; g < 4; ++g) {                                              \
      ACC[0][g] = MFMA(mm_a0, bfr[KC][g], ACC[0][g]);                          \
      ACC[1][g] = MFMA(mm_a1, bfr[KC][g], ACC[1][g]);                          \
    } }

// decoder kc=0 slice: bias rides the MFMA C-operand
#define MMH_KCD(ACC, X)                                                        \
  { const int mm_sl = ((l4 ^ l15) << 3);                                       \
    u16x8 mm_a0 = *(const u16x8*)&hL[(X)*4096 + l15 * 128 + mm_sl];            \
    u16x8 mm_a1 = *(const u16x8*)&hL[(X)*4096 + (16 + l15) * 128 + mm_sl];     \
    _Pragma("unroll")                                                          \
    for (int g = 0; g < 4; ++g) {                                              \
      ACC[0][g] = MFMA(mm_a0, bfr[0][g], bbV[g]);                              \
      ACC[1][g] = MFMA(mm_a1, bfr[0][g], bbV[g]);                              \
    } }

// encoder x-block: K=32 obs/bias fold, zero-C init
#define MMX_X(ACC, X)                                                          \
  { u16x8 mm_xa = *(const u16x8*)&A2[((X)*32 + l15) * A2S + l4 * 8];           \
    u16x8 mm_xb = *(const u16x8*)&A2[((X)*32 + 16 + l15) * A2S + l4 * 8];      \
    _Pragma("unroll")                                                          \
    for (int g = 0; g < 4; ++g) {                                              \
      ACC[0][g] = MFMA(mm_xa, xfr[g], ZROV);                                   \
      ACC[1][g] = MFMA(mm_xb, xfr[g], ZROV);                                   \
    } }

// one m-tile of the gate (f32x2 packed math); writes h rows of chunk X
#define GATEC_M(ACC, CRR, X, M)                                                \
  { _Pragma("unroll")                                                          \
    for (int hh = 0; hh < 2; ++hh) {                                           \
      f32x2 q_zi = (f32x2){ACC[M][0][2 * hh], ACC[M][0][2 * hh + 1]};          \
      f32x2 q_zf = (f32x2){ACC[M][1][2 * hh], ACC[M][1][2 * hh + 1]};          \
      f32x2 q_zg = (f32x2){ACC[M][2][2 * hh], ACC[M][2][2 * hh + 1]};          \
      f32x2 q_zo = (f32x2){ACC[M][3][2 * hh], ACC[M][3][2 * hh + 1]};          \
      f32x2 q_eB, q_eA, q_eG, q_eO;                                            \
      q_eB[0] = __builtin_amdgcn_exp2f(q_zi[0]);                               \
      q_eB[1] = __builtin_amdgcn_exp2f(q_zi[1]);                               \
      q_eA[0] = __builtin_amdgcn_exp2f(q_zf[0]);                               \
      q_eA[1] = __builtin_amdgcn_exp2f(q_zf[1]);                               \
      q_eG[0] = __builtin_amdgcn_exp2f(q_zg[0]);                               \
      q_eG[1] = __builtin_amdgcn_exp2f(q_zg[1]);                               \
      q_eO[0] = __builtin_amdgcn_exp2f(q_zo[0]);                               \
      q_eO[1] = __builtin_amdgcn_exp2f(q_zo[1]);                               \
      f32x2 q_a1 = 1.f + q_eA, q_b1 = 1.f + q_eB, q_g1 = 1.f + q_eG;           \
      f32x2 q_bg = q_b1 * q_g1;                                                \
      f32x2 q_dn = q_a1 * q_bg;                                                \
      f32x2 q_rd;                                                              \
      q_rd[0] = __builtin_amdgcn_rcpf(q_dn[0]);                                \
      q_rd[1] = __builtin_amdgcn_rcpf(q_dn[1]);                                \
      f32x2 q_cr = (f32x2){CRR[M][2 * hh], CRR[M][2 * hh + 1]};                \
      f32x2 q_cv = (q_cr * q_bg + (1.f - q_eG) * q_a1) * q_rd;                 \
      CRR[M][2 * hh] = q_cv[0]; CRR[M][2 * hh + 1] = q_cv[1];                  \
      f32x2 q_tC = q_cv * (-2.f * K2F);                                        \
      f32x2 q_eC;                                                              \
      q_eC[0] = __builtin_amdgcn_exp2f(q_tC[0]);                               \
      q_eC[1] = __builtin_amdgcn_exp2f(q_tC[1]);                               \
      f32x2 q_hd = (1.f + q_eO) * (1.f + q_eC);                                \
      f32x2 q_rh;                                                              \
      q_rh[0] = __builtin_amdgcn_rcpf(q_hd[0]);                                \
      q_rh[1] = __builtin_amdgcn_rcpf(q_hd[1]);                                \
      f32x2 q_h2 = (1.f - q_eC) * q_rh;                                        \
      const int q_R0 = 16 * (M) + l4 * 4 + 2 * hh;                             \
      hL[(X)*4096 + q_R0 * 128 + ((uh ^ (q_R0 & 15)) << 3) + ul] =             \
          cvt1(q_h2[0]);                                                       \
      hL[(X)*4096 + (q_R0 + 1) * 128 + ((uh ^ ((q_R0 + 1) & 15)) << 3) + ul] = \
          cvt1(q_h2[1]);                                                       \
    } }

// pos = h @ Wo + bo, fire-and-forget; Wo slice in regs wo0..wo3.
#define POSC(S, X)                                                             \
  { const int pp_r = tid >> 4;                                                 \
    u16x8 pp_h = *(const u16x8*)&hL[(X)*4096 + pp_r * 128 +                    \
                                    ((pq ^ (pp_r & 15)) << 3)];                \
    f32x2 pp_s = (f32x2){0.f, 0.f};                                            \
    pp_s += bf2f(pp_h[0]) * (f32x2){wo0[0], wo0[1]};                           \
    pp_s += bf2f(pp_h[1]) * (f32x2){wo0[2], wo0[3]};                           \
    pp_s += bf2f(pp_h[2]) * (f32x2){wo1[0], wo1[1]};                           \
    pp_s += bf2f(pp_h[3]) * (f32x2){wo1[2], wo1[3]};                           \
    pp_s += bf2f(pp_h[4]) * (f32x2){wo2[0], wo2[1]};                           \
    pp_s += bf2f(pp_h[5]) * (f32x2){wo2[2], wo2[3]};                           \
    pp_s += bf2f(pp_h[6]) * (f32x2){wo3[0], wo3[1]};                           \
    pp_s += bf2f(pp_h[7]) * (f32x2){wo3[2], wo3[3]};                           \
    pp_s[0] += __shfl_xor(pp_s[0], 1); pp_s[1] += __shfl_xor(pp_s[1], 1);      \
    pp_s[0] += __shfl_xor(pp_s[0], 2); pp_s[1] += __shfl_xor(pp_s[1], 2);      \
    pp_s[0] += __shfl_xor(pp_s[0], 4); pp_s[1] += __shfl_xor(pp_s[1], 4);      \
    pp_s[0] += __shfl_xor(pp_s[0], 8); pp_s[1] += __shfl_xor(pp_s[1], 8);      \
    if (pq == 0) {                                                             \
      float2 pp_o; pp_o.x = pp_s[0] + bo0; pp_o.y = pp_s[1] + bo1;             \
      ((float2*)out)[(size_t)(S)*BATCH + row0 + (X)*32 + pp_r] = pp_o;         \
    } }

// stage encoder A2 for chunk X, step T (exact hi/lo split)
#define STAGE_OBS_A2(T, X)                                                     \
  if (tid < 32) {                                                              \
    float2 so_p =                                                              \
        ((const float2*)obs)[(size_t)(T)*BATCH + row0 + (X)*32 + tid];         \
    unsigned short so_x = cvt1(so_p.x), so_y = cvt1(so_p.y);                   \
    unsigned short* so_r = &A2[((X)*32 + tid) * A2S];                          \
    so_r[0] = so_x; so_r[1] = so_y; so_r[2] = 0x3F80u;                         \
    so_r[3] = cvt1(so_p.x - bf2f(so_x));                                       \
    so_r[4] = cvt1(so_p.y - bf2f(so_y));                                       \
  }

__global__ __launch_bounds__(512, 2) void lstm_fused(
    const float* __restrict__ obs,
    const unsigned short* __restrict__ wt_enc,
    const unsigned short* __restrict__ wt_dec,
    const unsigned short* __restrict__ xw_enc,
    const float* __restrict__ auxf_dec,
    const float* __restrict__ Wo, const float* __restrict__ bo,
    float* __restrict__ out) {
  __shared__ unsigned short hL[2 * 32 * 128];   // 16 KB, 4-bit XOR-swizzled
  __shared__ unsigned short A2[2 * 32 * A2S];   // 5 KB

  const int tid = threadIdx.x;
  const int lane = tid & 63;
  const int cg = tid >> 6;          // wave 0..7 -> cols [64cg, 64cg+64)
  const int l15 = lane & 15;
  const int l4 = lane >> 4;
  const int pq = tid & 15;
  const int row0 = blockIdx.x * 64;
  const int u = cg * 16 + l15, uh = u >> 3, ul = u & 7;
  const float bo0 = bo[0], bo1 = bo[1];
  const f32x4 ZROV = {0.f, 0.f, 0.f, 0.f};

  // ---- P0: zero hL + A2; Wo slice + weights into regs ----
  {
    u16x8 z8 = (u16x8){0, 0, 0, 0, 0, 0, 0, 0};
    *(u16x8*)&hL[tid * 8] = z8;
    *(u16x8*)&hL[4096 + tid * 8] = z8;
    unsigned short* az = &A2[tid * 5];
    az[0] = 0; az[1] = 0; az[2] = 0; az[3] = 0; az[4] = 0;
  }
  const float* wop = Wo + pq * 16;
  const f32x4 wo0 = *(const f32x4*)wop;
  const f32x4 wo1 = *(const f32x4*)(wop + 4);
  const f32x4 wo2 = *(const f32x4*)(wop + 8);
  const f32x4 wo3 = *(const f32x4*)(wop + 12);

  u16x8 bfr[4][4], xfr[4];          // persistent weights: 80 regs
  LOADW_BF(wt_enc);
#pragma unroll
  for (int g = 0; g < 4; ++g)
    xfr[g] = *(const u16x8*)&xw_enc[(cg * 64 + g * 16 + l15) * XK + l4 * 8];

  f32x4 accA[2][4], accB[2][4];
  f32x4 crrA[2], crrB[2];
  crrA[0] = crrA[1] = ZROV;
  crrB[0] = crrB[1] = ZROV;
  f32x4 bbV[4];
  __syncthreads();

  // ---- P0b: stage A2_A(0). (A2_B(0) staged in alpha(0).) ----
  STAGE_OBS_A2(0, 0)
  __syncthreads();

  // ---- encoder t = 0..7, interleaved phases ----
#pragma unroll 1
  for (int t = 0; t < OBS_LEN; ++t) {
    // alpha(t): GATE_B(t-1) || MM_A(t); stage A2_B(t)
    if (t > 0) { GATEC_M(accB, crrB, 1, 0) }
    MMX_X(accA, 0)
    if (t > 0) { GATEC_M(accB, crrB, 1, 1) }
    MMH_KC(accA, 0, 0)
    STAGE_OBS_A2(t, 1)
    MMH_KC(accA, 0, 1)
    MMH_KC(accA, 0, 2)
    MMH_KC(accA, 0, 3)
    __syncthreads();
    // beta(t): GATE_A(t) || MM_B(t); stage A2_A(t+1)
    GATEC_M(accA, crrA, 0, 0)
    MMX_X(accB, 1)
    GATEC_M(accA, crrA, 0, 1)
    MMH_KC(accB, 1, 0)
    if (t + 1 < OBS_LEN) { STAGE_OBS_A2(t + 1, 0) }
    MMH_KC(accB, 1, 1)
    MMH_KC(accB, 1, 2)
    MMH_KC(accB, 1, 3)
    __syncthreads();
  }

  // ---- transition: decoder weights + bias vec; reset c for chunk A ----
  LOADW_BF(wt_dec);
#pragma unroll
  for (int g = 0; g < 4; ++g) {
    float b_ = auxf_dec[cg * 64 + g * 16 + l15];
    bbV[g] = (f32x4){b_, b_, b_, b_};
  }
  crrA[0] = crrA[1] = ZROV;

  // alpha_d(1): GATE_B(7,enc) || dec MM_A(1); POSC_A(0)
  GATEC_M(accB, crrB, 1, 0)
  MMH_KCD(accA, 0)
  GATEC_M(accB, crrB, 1, 1)
  MMH_KC(accA, 0, 1)
  POSC(0, 0)
  MMH_KC(accA, 0, 2)
  MMH_KC(accA, 0, 3)
  __syncthreads();
  crrB[0] = crrB[1] = ZROV;

  // beta_d(1): GATE_A^dec(1) || dec MM_B(1); POSC_B(0)
  GATEC_M(accA, crrA, 0, 0)
  MMH_KCD(accB, 1)
  GATEC_M(accA, crrA, 0, 1)
  MMH_KC(accB, 1, 1)
  POSC(0, 1)
  MMH_KC(accB, 1, 2)
  MMH_KC(accB, 1, 3)
  __syncthreads();

  // ---- decoder d = 2..11 ----
#pragma unroll 1
  for (int d = 2; d < PRED_LEN; ++d) {
    GATEC_M(accB, crrB, 1, 0)
    MMH_KCD(accA, 0)
    GATEC_M(accB, crrB, 1, 1)
    MMH_KC(accA, 0, 1)
    POSC(d - 1, 0)
    MMH_KC(accA, 0, 2)
    MMH_KC(accA, 0, 3)
    __syncthreads();
    GATEC_M(accA, crrA, 0, 0)
    MMH_KCD(accB, 1)
    GATEC_M(accA, crrA, 0, 1)
    MMH_KC(accB, 1, 1)
    POSC(d - 1, 1)
    MMH_KC(accB, 1, 2)
    MMH_KC(accB, 1, 3)
    __syncthreads();
  }

  // ---- epilogue ----
  GATEC_M(accB, crrB, 1, 0)
  GATEC_M(accB, crrB, 1, 1)
  POSC(PRED_LEN - 1, 0)
  __syncthreads();
  POSC(PRED_LEN - 1, 1)
}

extern "C" void kernel_launch(void* const* d_in, const int* in_sizes, int n_in,
                              void* d_out, int out_size, void* d_ws, size_t ws_size,
                              hipStream_t stream) {
  const float* obs   = (const float*)d_in[0];
  const float* We    = (const float*)d_in[1];
  const float* be    = (const float*)d_in[2];
  const float* Wih_e = (const float*)d_in[3];
  const float* Whh_e = (const float*)d_in[4];
  const float* b_e   = (const float*)d_in[5];
  const float* Wd    = (const float*)d_in[6];
  const float* bd    = (const float*)d_in[7];
  const float* Wih_d = (const float*)d_in[8];
  const float* Whh_d = (const float*)d_in[9];
  const float* b_d   = (const float*)d_in[10];
  const float* Wo    = (const float*)d_in[11];
  const float* bo    = (const float*)d_in[12];
  float* out = (float*)d_out;

  unsigned short* wt_enc = (unsigned short*)d_ws;                 // 128 KB
  unsigned short* wt_dec = wt_enc + NZ * KWT;                     // +128 KB
  unsigned short* xw_enc = wt_dec + NZ * KWT;                     // +32 KB
  float* auxf_dec = (float*)(xw_enc + NZ * XK);                   // +2 KB

  hipLaunchKernelGGL(prep_weights, dim3(2 * NZ), dim3(64), 0, stream,
                     We, be, Wih_e, Whh_e, b_e, Wd, bd, Wih_d, Whh_d, b_d,
                     Wo, bo, wt_enc, wt_dec, xw_enc, auxf_dec);
  hipLaunchKernelGGL(lstm_fused, dim3(BATCH / 64), dim3(512), 0, stream,
                     obs, wt_enc, wt_dec, xw_enc, auxf_dec, Wo, bo, out);
}